// Round 3
// baseline (273.451 us; speedup 1.0000x reference)
//
#include <hip/hip_runtime.h>
#include <hip/hip_bf16.h>
#include <stdint.h>

#define B_DIM 128
#define N_DIM 16384
#define E_DIM 1048576
#define H_DIM 512
#define C_DIM 10
#define NWG 256               // wgs for hist/place
#define CHUNK (E_DIM / NWG)   // 4096 edges per wg
#define NWORD (N_DIM / 2)     // 8192 packed uint words (2 bins each)
#define NGRP 8                // scan groups
#define WPG (NWG / NGRP)      // 32 wgs per group
#define SPLITK 64
#define KC (N_DIM / SPLITK)   // 256
#define BM 64
#define KB 16

// ---------- transpose x (B,N) -> xT (N,B) ----------
__global__ void k_transpose(const float* __restrict__ x, float* __restrict__ xT) {
    __shared__ float tile[32][33];
    int bx = blockIdx.x, by = blockIdx.y;
    int tx = threadIdx.x, ty = threadIdx.y;
    int n = bx * 32 + tx, b = by * 32 + ty;
    tile[ty][tx] = x[b * N_DIM + n];
    __syncthreads();
    int n2 = bx * 32 + ty, b2 = by * 32 + tx;
    xT[n2 * B_DIM + b2] = tile[tx][ty];
}

// ---------- per-wg LDS histogram of dst (2x16-bit packed), flush to slab ----------
__global__ void __launch_bounds__(256) k_hist1(const int* __restrict__ dst,
                                               uint32_t* __restrict__ slab) {
    __shared__ uint32_t lh[NWORD];   // 32 KB
    int w = blockIdx.x, t = threadIdx.x;
#pragma unroll
    for (int i = 0; i < NWORD / 256; i++) lh[i * 256 + t] = 0;
    __syncthreads();
#pragma unroll
    for (int i = 0; i < CHUNK / 256; i++) {
        int d = dst[w * CHUNK + i * 256 + t];
        atomicAdd(&lh[d >> 1], 1u << ((d & 1) << 4));
    }
    __syncthreads();
#pragma unroll
    for (int i = 0; i < NWORD / 256; i++)
        slab[(size_t)w * NWORD + i * 256 + t] = lh[i * 256 + t];
}

// ---------- within-group (32 wgs) in-place exclusive prefix; per-group totals ----------
__global__ void __launch_bounds__(256) k_scanA(uint32_t* __restrict__ slab,
                                               uint32_t* __restrict__ grp) {
    int b = blockIdx.x;                 // 0..255
    int g = b >> 5;                     // group 0..7
    int j = (b & 31) * 256 + threadIdx.x;  // word 0..8191
    uint32_t lo = 0, hi = 0;
    for (int w = g * WPG; w < (g + 1) * WPG; w++) {
        uint32_t c = slab[(size_t)w * NWORD + j];
        slab[(size_t)w * NWORD + j] = lo | (hi << 16);
        lo += c & 0xffffu;
        hi += c >> 16;
    }
    grp[(size_t)g * NWORD + j] = lo | (hi << 16);
}

// ---------- cross-group exclusive prefix; bin totals ----------
__global__ void __launch_bounds__(256) k_scanB(uint32_t* __restrict__ grp,
                                               uint32_t* __restrict__ binTot) {
    int j = blockIdx.x * 256 + threadIdx.x;   // word 0..8191
    uint32_t lo = 0, hi = 0;
#pragma unroll
    for (int g = 0; g < NGRP; g++) {
        uint32_t c = grp[(size_t)g * NWORD + j];
        grp[(size_t)g * NWORD + j] = lo | (hi << 16);
        lo += c & 0xffffu;
        hi += c >> 16;
    }
    binTot[j] = lo | (hi << 16);
}

// ---------- single-wg exclusive scan of bin totals -> CSR offs ----------
__global__ void __launch_bounds__(1024) k_scan2b(const uint32_t* __restrict__ binTot,
                                                 int* __restrict__ offs) {
    __shared__ uint32_t part[1024];
    int t = threadIdx.x;
    uint32_t loc[16];
    uint32_t s = 0;
    int wbase = t * 8;
#pragma unroll
    for (int i = 0; i < 8; i++) {
        uint32_t wv = binTot[wbase + i];
        loc[2 * i] = s;     s += (wv & 0xffffu);
        loc[2 * i + 1] = s; s += (wv >> 16);
    }
    part[t] = s;
    __syncthreads();
    for (int off = 1; off < 1024; off <<= 1) {
        uint32_t v = (t >= off) ? part[t - off] : 0;
        __syncthreads();
        part[t] += v;
        __syncthreads();
    }
    uint32_t ex = (t == 0) ? 0 : part[t - 1];
#pragma unroll
    for (int i = 0; i < 16; i++) offs[t * 16 + i] = (int)(ex + loc[i]);
    if (t == 1023) offs[N_DIM] = (int)part[1023];
}

// ---------- atomic-free (global) placement: LDS cursor per wg ----------
__global__ void __launch_bounds__(256) k_place2(const int* __restrict__ src,
                                                const int* __restrict__ dst,
                                                const float* __restrict__ ew,
                                                const uint32_t* __restrict__ slab,
                                                const uint32_t* __restrict__ grp,
                                                const int* __restrict__ offs,
                                                int2* __restrict__ packed) {
    __shared__ uint32_t cur[N_DIM];   // 64 KB
    int w = blockIdx.x, t = threadIdx.x;
    int g = w >> 5;
#pragma unroll
    for (int i = 0; i < NWORD / 256; i++) {
        int j = i * 256 + t;
        uint32_t pv = slab[(size_t)w * NWORD + j];
        uint32_t gv = grp[(size_t)g * NWORD + j];
        int2 o = *(const int2*)&offs[2 * j];
        cur[2 * j]     = (uint32_t)o.x + (gv & 0xffffu) + (pv & 0xffffu);
        cur[2 * j + 1] = (uint32_t)o.y + (gv >> 16) + (pv >> 16);
    }
    __syncthreads();
#pragma unroll
    for (int i = 0; i < CHUNK / 256; i++) {
        int e = w * CHUNK + i * 256 + t;
        int s = src[e], d = dst[e];
        uint32_t pos = atomicAdd(&cur[d], 1u);   // LDS atomic
        packed[pos] = make_int2(s, __float_as_int(ew[e]));
    }
}

// ---------- per-node weighted in-degree from sorted segments -> dinv ----------
__global__ void __launch_bounds__(64) k_deg(const int* __restrict__ offs,
                                            const int2* __restrict__ packed,
                                            float* __restrict__ dinv) {
    int d = blockIdx.x, lane = threadIdx.x;
    int e0 = offs[d], e1 = offs[d + 1];
    float s = 0.f;
    for (int e = e0 + lane; e < e1; e += 64)
        s += __int_as_float(packed[e].y);
#pragma unroll
    for (int off = 32; off > 0; off >>= 1) s += __shfl_down(s, off);
    if (lane == 0) dinv[d] = rsqrtf(s + 1.0f);   // + self-loop weight 1; always > 0
}

// ---------- diffusion: XCD-pinned batch slice, 4 edges/iter ----------
// grid = N_DIM*8; slice = bid&7 rides the round-robin block->XCD mapping so each
// XCD's gather working set is a 1 MB xT column-slice (L2-resident).
__global__ void __launch_bounds__(64) k_diffuse(const float* __restrict__ xT,
                                                const int* __restrict__ offs,
                                                const int2* __restrict__ packed,
                                                const float* __restrict__ dinv,
                                                float* __restrict__ hT) {
    int bid = blockIdx.x;
    int slice = bid & 7;
    int d = bid >> 3;
    int lane = threadIdx.x;
    int g = lane >> 4;          // edge subgroup 0..3
    int col = slice * 16 + (lane & 15);
    __shared__ int2 buf[64];
    float dv = dinv[d];
    float acc = (g == 0) ? dv * xT[d * B_DIM + col] : 0.f;   // self-loop (x dv at end)
    int e0 = offs[d], e1 = offs[d + 1];
    for (int base = e0; base < e1; base += 64) {
        int cnt = e1 - base;
        if (cnt > 64) cnt = 64;
        if (lane < cnt) {
            int2 p = packed[base + lane];
            p.y = __float_as_int(__int_as_float(p.y) * dinv[p.x]);  // fold dinv[src]*w
            buf[lane] = p;
        }
        __syncthreads();
        for (int i = 0; i < cnt; i += 4) {
            if (i + g < cnt) {
                int2 p = buf[i + g];
                acc = fmaf(__int_as_float(p.y), xT[p.x * B_DIM + col], acc);
            }
        }
        __syncthreads();
    }
    acc += __shfl_xor(acc, 16);
    acc += __shfl_xor(acc, 32);
    if (lane < 16) hT[d * B_DIM + col] = acc * dv;
}

// ---------- GEMM1: W1(512,16384) x hT(16384,128) split-K partials ----------
__global__ void __launch_bounds__(256) k_gemm1(const float* __restrict__ W1,
                                               const float* __restrict__ hT,
                                               float* __restrict__ part) {
    int mt = blockIdx.x;   // 0..7
    int kc = blockIdx.y;   // 0..SPLITK-1
    int t = threadIdx.x;
    __shared__ float Ws[KB][BM];     // 16 x 64
    __shared__ float Hs[KB][B_DIM];  // 16 x 128
    int tn = t & 31;   // col group (*4)
    int tm = t >> 5;   // row group (*8)
    float acc[8][4];
#pragma unroll
    for (int i = 0; i < 8; i++)
#pragma unroll
        for (int j = 0; j < 4; j++) acc[i][j] = 0.f;
    int m0 = mt * BM;
    int k0 = kc * KC;
    int wr = t >> 2;         // 0..63 W row
    int wq = (t & 3) * 4;    // k quad
    int hr = t >> 4;         // 0..15 k row
    int hc = (t & 15) * 8;   // col (*8)
    for (int ks = 0; ks < KC; ks += KB) {
        float4 wv = *(const float4*)&W1[(size_t)(m0 + wr) * N_DIM + k0 + ks + wq];
        float4 h0 = *(const float4*)&hT[(k0 + ks + hr) * B_DIM + hc];
        float4 h1 = *(const float4*)&hT[(k0 + ks + hr) * B_DIM + hc + 4];
        __syncthreads();
        Ws[wq + 0][wr] = wv.x;
        Ws[wq + 1][wr] = wv.y;
        Ws[wq + 2][wr] = wv.z;
        Ws[wq + 3][wr] = wv.w;
        *(float4*)&Hs[hr][hc] = h0;
        *(float4*)&Hs[hr][hc + 4] = h1;
        __syncthreads();
#pragma unroll
        for (int kk = 0; kk < KB; kk++) {
            float a[8], b[4];
            *(float4*)&a[0] = *(const float4*)&Ws[kk][tm * 8];
            *(float4*)&a[4] = *(const float4*)&Ws[kk][tm * 8 + 4];
            *(float4*)&b[0] = *(const float4*)&Hs[kk][tn * 4];
#pragma unroll
            for (int i = 0; i < 8; i++)
#pragma unroll
                for (int j = 0; j < 4; j++)
                    acc[i][j] = fmaf(a[i], b[j], acc[i][j]);
        }
    }
    float* pbase = part + (size_t)kc * (H_DIM * B_DIM);
#pragma unroll
    for (int i = 0; i < 8; i++)
        *(float4*)&pbase[(m0 + tm * 8 + i) * B_DIM + tn * 4] = *(float4*)&acc[i][0];
}

// ---------- reduce split-K partials + bias + relu ----------
__global__ void k_reduce1(const float* __restrict__ part, const float* __restrict__ b1,
                          float* __restrict__ h1T) {
    int idx = blockIdx.x * 256 + threadIdx.x;  // 0..65535
    int j = idx >> 7;
    float s = b1[j];
#pragma unroll
    for (int c = 0; c < SPLITK; c++) s += part[c * (H_DIM * B_DIM) + idx];
    h1T[idx] = fmaxf(s, 0.f);
}

// ---------- GEMM2: W2(512,512) x h1T(512,128) + relu ----------
__global__ void __launch_bounds__(256) k_gemm2(const float* __restrict__ W2,
                                               const float* __restrict__ b2,
                                               const float* __restrict__ h1T,
                                               float* __restrict__ h2T) {
    int t = threadIdx.x;
    int b = t & 127;
    int j = blockIdx.x * 2 + (t >> 7);
    const float* wrow = W2 + j * H_DIM;
    float s = b2[j];
#pragma unroll 4
    for (int i = 0; i < H_DIM; i++)
        s = fmaf(wrow[i], h1T[i * B_DIM + b], s);
    h2T[j * B_DIM + b] = fmaxf(s, 0.f);
}

// ---------- GEMM3: Wfc(10,512) x h2T(512,128) -> out (128,10) ----------
__global__ void __launch_bounds__(128) k_gemm3(const float* __restrict__ Wfc,
                                               const float* __restrict__ bfc,
                                               const float* __restrict__ h2T,
                                               float* __restrict__ out) {
    int c = blockIdx.x;
    int b = threadIdx.x;
    const float* wrow = Wfc + c * H_DIM;
    float s = bfc[c];
#pragma unroll 4
    for (int i = 0; i < H_DIM; i++)
        s = fmaf(wrow[i], h2T[i * B_DIM + b], s);
    out[b * C_DIM + c] = s;
}

extern "C" void kernel_launch(void* const* d_in, const int* in_sizes, int n_in,
                              void* d_out, int out_size, void* d_ws, size_t ws_size,
                              hipStream_t stream) {
    const float* x   = (const float*)d_in[0];
    const int*   ei  = (const int*)d_in[1];
    const float* ew  = (const float*)d_in[2];
    const float* W1  = (const float*)d_in[3];
    const float* b1  = (const float*)d_in[4];
    const float* W2  = (const float*)d_in[5];
    const float* b2  = (const float*)d_in[6];
    const float* Wfc = (const float*)d_in[7];
    const float* bfc = (const float*)d_in[8];
    float* out = (float*)d_out;

    const int* src = ei;
    const int* dst = ei + E_DIM;

    char* ws = (char*)d_ws;
    size_t off = 0;
    auto alloc = [&](size_t bytes) -> void* {
        void* p = ws + off;
        off = (off + bytes + 255) & ~(size_t)255;
        return p;
    };
    float* xT     = (float*)alloc((size_t)N_DIM * B_DIM * 4);          // 8 MB
    float* hT     = (float*)alloc((size_t)N_DIM * B_DIM * 4);          // 8 MB
    int2*  packed = (int2*) alloc((size_t)E_DIM * 8);                  // 8 MB
    float* part   = (float*)alloc((size_t)SPLITK * H_DIM * B_DIM * 4); // 16 MB
    float* h1T    = (float*)alloc((size_t)H_DIM * B_DIM * 4);
    float* h2T    = (float*)alloc((size_t)H_DIM * B_DIM * 4);
    int*   offs   = (int*)  alloc((size_t)(N_DIM + 1) * 4);
    float* dinv   = (float*)alloc((size_t)N_DIM * 4);
    // slab (8 MB) + grp (256 KB) + binTot (32 KB) alias 'part': lifetimes
    // (hist1..place2) vs (gemm1..reduce1) are disjoint.
    uint32_t* slab   = (uint32_t*)part;
    uint32_t* grp    = (uint32_t*)((char*)part + (size_t)NWG * NWORD * 4);
    uint32_t* binTot = (uint32_t*)((char*)part + (size_t)NWG * NWORD * 4 + (size_t)NGRP * NWORD * 4);
    if (off > ws_size) return;

    k_transpose<<<dim3(N_DIM / 32, B_DIM / 32), dim3(32, 32), 0, stream>>>(x, xT);
    k_hist1<<<NWG, 256, 0, stream>>>(dst, slab);
    k_scanA<<<NWORD * NGRP / 256, 256, 0, stream>>>(slab, grp);
    k_scanB<<<NWORD / 256, 256, 0, stream>>>(grp, binTot);
    k_scan2b<<<1, 1024, 0, stream>>>(binTot, offs);
    k_place2<<<NWG, 256, 0, stream>>>(src, dst, ew, slab, grp, offs, packed);
    k_deg<<<N_DIM, 64, 0, stream>>>(offs, packed, dinv);
    k_diffuse<<<N_DIM * 8, 64, 0, stream>>>(xT, offs, packed, dinv, hT);
    k_gemm1<<<dim3(H_DIM / BM, SPLITK), 256, 0, stream>>>(W1, hT, part);
    k_reduce1<<<(H_DIM * B_DIM) / 256, 256, 0, stream>>>(part, b1, h1T);
    k_gemm2<<<H_DIM / 2, 256, 0, stream>>>(W2, b2, h1T, h2T);
    k_gemm3<<<C_DIM, 128, 0, stream>>>(Wfc, bfc, h2T, out);
}

// Round 4
// 235.635 us; speedup vs baseline: 1.1605x; 1.1605x over previous
//
#include <hip/hip_runtime.h>
#include <hip/hip_bf16.h>
#include <stdint.h>

#define B_DIM 128
#define N_DIM 16384
#define E_DIM 1048576
#define H_DIM 512
#define C_DIM 10
#define NWG 256               // wgs for hist/place
#define CHUNK (E_DIM / NWG)   // 4096 edges per wg
#define NWORD (N_DIM / 2)     // 8192 packed uint words (2 bins each)
#define NGRP 8                // scan groups
#define WPG (NWG / NGRP)      // 32 wgs per group
#define NSLICE 4              // diffusion column slices (32 cols = 2 MB each)
#define SPLITK 32
#define KC (N_DIM / SPLITK)   // 512
#define BM 64
#define KB 16

// ---------- transpose x (B,N) -> xT (N,B) ----------
__global__ void k_transpose(const float* __restrict__ x, float* __restrict__ xT) {
    __shared__ float tile[32][33];
    int bx = blockIdx.x, by = blockIdx.y;
    int tx = threadIdx.x, ty = threadIdx.y;
    int n = bx * 32 + tx, b = by * 32 + ty;
    tile[ty][tx] = x[b * N_DIM + n];
    __syncthreads();
    int n2 = bx * 32 + ty, b2 = by * 32 + tx;
    xT[n2 * B_DIM + b2] = tile[tx][ty];
}

// ---------- per-wg LDS histogram of dst (2x16-bit packed), flush to slab ----------
__global__ void __launch_bounds__(256) k_hist1(const int* __restrict__ dst,
                                               uint32_t* __restrict__ slab) {
    __shared__ uint32_t lh[NWORD];   // 32 KB
    int w = blockIdx.x, t = threadIdx.x;
#pragma unroll
    for (int i = 0; i < NWORD / 256; i++) lh[i * 256 + t] = 0;
    __syncthreads();
#pragma unroll
    for (int i = 0; i < CHUNK / 256; i++) {
        int d = dst[w * CHUNK + i * 256 + t];
        atomicAdd(&lh[d >> 1], 1u << ((d & 1) << 4));
    }
    __syncthreads();
#pragma unroll
    for (int i = 0; i < NWORD / 256; i++)
        slab[(size_t)w * NWORD + i * 256 + t] = lh[i * 256 + t];
}

// ---------- within-group (32 wgs) in-place exclusive prefix; per-group totals ----------
__global__ void __launch_bounds__(256) k_scanA(uint32_t* __restrict__ slab,
                                               uint32_t* __restrict__ grp) {
    int b = blockIdx.x;                 // 0..255
    int g = b >> 5;                     // group 0..7
    int j = (b & 31) * 256 + threadIdx.x;  // word 0..8191
    uint32_t lo = 0, hi = 0;
    for (int w = g * WPG; w < (g + 1) * WPG; w++) {
        uint32_t c = slab[(size_t)w * NWORD + j];
        slab[(size_t)w * NWORD + j] = lo | (hi << 16);
        lo += c & 0xffffu;
        hi += c >> 16;
    }
    grp[(size_t)g * NWORD + j] = lo | (hi << 16);
}

// ---------- cross-group exclusive prefix; bin totals ----------
__global__ void __launch_bounds__(256) k_scanB(uint32_t* __restrict__ grp,
                                               uint32_t* __restrict__ binTot) {
    int j = blockIdx.x * 256 + threadIdx.x;   // word 0..8191
    uint32_t lo = 0, hi = 0;
#pragma unroll
    for (int g = 0; g < NGRP; g++) {
        uint32_t c = grp[(size_t)g * NWORD + j];
        grp[(size_t)g * NWORD + j] = lo | (hi << 16);
        lo += c & 0xffffu;
        hi += c >> 16;
    }
    binTot[j] = lo | (hi << 16);
}

// ---------- single-wg exclusive scan of bin totals -> CSR offs ----------
__global__ void __launch_bounds__(1024) k_scan2b(const uint32_t* __restrict__ binTot,
                                                 int* __restrict__ offs) {
    __shared__ uint32_t part[1024];
    int t = threadIdx.x;
    uint32_t loc[16];
    uint32_t s = 0;
    int wbase = t * 8;
#pragma unroll
    for (int i = 0; i < 8; i++) {
        uint32_t wv = binTot[wbase + i];
        loc[2 * i] = s;     s += (wv & 0xffffu);
        loc[2 * i + 1] = s; s += (wv >> 16);
    }
    part[t] = s;
    __syncthreads();
    for (int off = 1; off < 1024; off <<= 1) {
        uint32_t v = (t >= off) ? part[t - off] : 0;
        __syncthreads();
        part[t] += v;
        __syncthreads();
    }
    uint32_t ex = (t == 0) ? 0 : part[t - 1];
#pragma unroll
    for (int i = 0; i < 16; i++) offs[t * 16 + i] = (int)(ex + loc[i]);
    if (t == 1023) offs[N_DIM] = (int)part[1023];
}

// ---------- atomic-free (global) placement: LDS cursor per wg ----------
__global__ void __launch_bounds__(256) k_place2(const int* __restrict__ src,
                                                const int* __restrict__ dst,
                                                const float* __restrict__ ew,
                                                const uint32_t* __restrict__ slab,
                                                const uint32_t* __restrict__ grp,
                                                const int* __restrict__ offs,
                                                int2* __restrict__ packed) {
    __shared__ uint32_t cur[N_DIM];   // 64 KB
    int w = blockIdx.x, t = threadIdx.x;
    int g = w >> 5;
#pragma unroll
    for (int i = 0; i < NWORD / 256; i++) {
        int j = i * 256 + t;
        uint32_t pv = slab[(size_t)w * NWORD + j];
        uint32_t gv = grp[(size_t)g * NWORD + j];
        int2 o = *(const int2*)&offs[2 * j];
        cur[2 * j]     = (uint32_t)o.x + (gv & 0xffffu) + (pv & 0xffffu);
        cur[2 * j + 1] = (uint32_t)o.y + (gv >> 16) + (pv >> 16);
    }
    __syncthreads();
#pragma unroll
    for (int i = 0; i < CHUNK / 256; i++) {
        int e = w * CHUNK + i * 256 + t;
        int s = src[e], d = dst[e];
        uint32_t pos = atomicAdd(&cur[d], 1u);   // LDS atomic
        packed[pos] = make_int2(s, __float_as_int(ew[e]));
    }
}

// ---------- per-node weighted in-degree from sorted segments -> dinv ----------
__global__ void __launch_bounds__(64) k_deg(const int* __restrict__ offs,
                                            const int2* __restrict__ packed,
                                            float* __restrict__ dinv) {
    int d = blockIdx.x, lane = threadIdx.x;
    int e0 = offs[d], e1 = offs[d + 1];
    float s = 0.f;
    for (int e = e0 + lane; e < e1; e += 64)
        s += __int_as_float(packed[e].y);
#pragma unroll
    for (int off = 32; off > 0; off >>= 1) s += __shfl_down(s, off);
    if (lane == 0) dinv[d] = rsqrtf(s + 1.0f);   // + self-loop weight 1; always > 0
}

// ---------- diffusion: 4 XCD-pinned column slices, 4 edges per wave-instr ----------
// grid = N_DIM*NSLICE. slice = bid&3: XCD k (blocks bid%8==k) only touches column
// slice k&3, a 2 MB xT stripe -> L2-resident. Full 64-lane loads: 4 edge groups
// x 16 lanes x float2 = 512 B per gather instruction (1 load-instr per edge total).
__global__ void __launch_bounds__(64) k_diffuse(const float* __restrict__ xT,
                                                const int* __restrict__ offs,
                                                const int2* __restrict__ packed,
                                                const float* __restrict__ dinv,
                                                float* __restrict__ hT) {
    int bid = blockIdx.x;
    int slice = bid & (NSLICE - 1);
    int d = bid >> 2;
    int lane = threadIdx.x;
    int g = lane >> 4;                 // edge subgroup 0..3
    int c = lane & 15;                 // float2 column within slice
    int colv = slice * 16 + c;         // float2 index within row (64 per row)
    __shared__ int2 buf[64];
    const float2* x2 = (const float2*)xT;
    float dv = dinv[d];
    float2 acc = make_float2(0.f, 0.f);
    if (g == 0) {
        float2 xv = x2[d * 64 + colv];
        acc.x = dv * xv.x; acc.y = dv * xv.y;   // self-loop (x dv at end)
    }
    int e0 = offs[d], e1 = offs[d + 1];
    for (int base = e0; base < e1; base += 64) {
        int cnt = e1 - base;
        if (cnt > 64) cnt = 64;
        if (lane < cnt) {
            int2 p = packed[base + lane];
            p.y = __float_as_int(__int_as_float(p.y) * dinv[p.x]);  // fold dinv[src]*w
            buf[lane] = p;
        }
        __syncthreads();
        for (int i = 0; i < cnt; i += 4) {
            if (i + g < cnt) {
                int2 p = buf[i + g];
                float nrm = __int_as_float(p.y);
                float2 xs = x2[p.x * 64 + colv];
                acc.x = fmaf(nrm, xs.x, acc.x);
                acc.y = fmaf(nrm, xs.y, acc.y);
            }
        }
        __syncthreads();
    }
    acc.x += __shfl_xor(acc.x, 16);
    acc.x += __shfl_xor(acc.x, 32);
    acc.y += __shfl_xor(acc.y, 16);
    acc.y += __shfl_xor(acc.y, 32);
    if (lane < 16) {
        acc.x *= dv; acc.y *= dv;
        ((float2*)hT)[d * 64 + colv] = acc;
    }
}

// ---------- GEMM1: W1(512,16384) x hT(16384,128) split-K partials ----------
__global__ void __launch_bounds__(256) k_gemm1(const float* __restrict__ W1,
                                               const float* __restrict__ hT,
                                               float* __restrict__ part) {
    int mt = blockIdx.x;   // 0..7
    int kc = blockIdx.y;   // 0..SPLITK-1
    int t = threadIdx.x;
    __shared__ float Ws[KB][BM];     // 16 x 64
    __shared__ float Hs[KB][B_DIM];  // 16 x 128
    int tn = t & 31;   // col group (*4)
    int tm = t >> 5;   // row group (*8)
    float acc[8][4];
#pragma unroll
    for (int i = 0; i < 8; i++)
#pragma unroll
        for (int j = 0; j < 4; j++) acc[i][j] = 0.f;
    int m0 = mt * BM;
    int k0 = kc * KC;
    int wr = t >> 2;         // 0..63 W row
    int wq = (t & 3) * 4;    // k quad
    int hr = t >> 4;         // 0..15 k row
    int hc = (t & 15) * 8;   // col (*8)
    for (int ks = 0; ks < KC; ks += KB) {
        float4 wv = *(const float4*)&W1[(size_t)(m0 + wr) * N_DIM + k0 + ks + wq];
        float4 h0 = *(const float4*)&hT[(k0 + ks + hr) * B_DIM + hc];
        float4 h1 = *(const float4*)&hT[(k0 + ks + hr) * B_DIM + hc + 4];
        __syncthreads();
        Ws[wq + 0][wr] = wv.x;
        Ws[wq + 1][wr] = wv.y;
        Ws[wq + 2][wr] = wv.z;
        Ws[wq + 3][wr] = wv.w;
        *(float4*)&Hs[hr][hc] = h0;
        *(float4*)&Hs[hr][hc + 4] = h1;
        __syncthreads();
#pragma unroll
        for (int kk = 0; kk < KB; kk++) {
            float a[8], b[4];
            *(float4*)&a[0] = *(const float4*)&Ws[kk][tm * 8];
            *(float4*)&a[4] = *(const float4*)&Ws[kk][tm * 8 + 4];
            *(float4*)&b[0] = *(const float4*)&Hs[kk][tn * 4];
#pragma unroll
            for (int i = 0; i < 8; i++)
#pragma unroll
                for (int j = 0; j < 4; j++)
                    acc[i][j] = fmaf(a[i], b[j], acc[i][j]);
        }
    }
    float* pbase = part + (size_t)kc * (H_DIM * B_DIM);
#pragma unroll
    for (int i = 0; i < 8; i++)
        *(float4*)&pbase[(m0 + tm * 8 + i) * B_DIM + tn * 4] = *(float4*)&acc[i][0];
}

// ---------- reduce split-K partials + bias + relu ----------
__global__ void k_reduce1(const float* __restrict__ part, const float* __restrict__ b1,
                          float* __restrict__ h1T) {
    int idx = blockIdx.x * 256 + threadIdx.x;  // 0..65535
    int j = idx >> 7;
    float s = b1[j];
#pragma unroll
    for (int c = 0; c < SPLITK; c++) s += part[c * (H_DIM * B_DIM) + idx];
    h1T[idx] = fmaxf(s, 0.f);
}

// ---------- GEMM2: W2(512,512) x h1T(512,128) + relu ----------
__global__ void __launch_bounds__(256) k_gemm2(const float* __restrict__ W2,
                                               const float* __restrict__ b2,
                                               const float* __restrict__ h1T,
                                               float* __restrict__ h2T) {
    int t = threadIdx.x;
    int b = t & 127;
    int j = blockIdx.x * 2 + (t >> 7);
    const float* wrow = W2 + j * H_DIM;
    float s = b2[j];
#pragma unroll 4
    for (int i = 0; i < H_DIM; i++)
        s = fmaf(wrow[i], h1T[i * B_DIM + b], s);
    h2T[j * B_DIM + b] = fmaxf(s, 0.f);
}

// ---------- GEMM3: Wfc(10,512) x h2T(512,128) -> out (128,10) ----------
__global__ void __launch_bounds__(128) k_gemm3(const float* __restrict__ Wfc,
                                               const float* __restrict__ bfc,
                                               const float* __restrict__ h2T,
                                               float* __restrict__ out) {
    int c = blockIdx.x;
    int b = threadIdx.x;
    const float* wrow = Wfc + c * H_DIM;
    float s = bfc[c];
#pragma unroll 4
    for (int i = 0; i < H_DIM; i++)
        s = fmaf(wrow[i], h2T[i * B_DIM + b], s);
    out[b * C_DIM + c] = s;
}

extern "C" void kernel_launch(void* const* d_in, const int* in_sizes, int n_in,
                              void* d_out, int out_size, void* d_ws, size_t ws_size,
                              hipStream_t stream) {
    const float* x   = (const float*)d_in[0];
    const int*   ei  = (const int*)d_in[1];
    const float* ew  = (const float*)d_in[2];
    const float* W1  = (const float*)d_in[3];
    const float* b1  = (const float*)d_in[4];
    const float* W2  = (const float*)d_in[5];
    const float* b2  = (const float*)d_in[6];
    const float* Wfc = (const float*)d_in[7];
    const float* bfc = (const float*)d_in[8];
    float* out = (float*)d_out;

    const int* src = ei;
    const int* dst = ei + E_DIM;

    char* ws = (char*)d_ws;
    size_t off = 0;
    auto alloc = [&](size_t bytes) -> void* {
        void* p = ws + off;
        off = (off + bytes + 255) & ~(size_t)255;
        return p;
    };
    float* xT     = (float*)alloc((size_t)N_DIM * B_DIM * 4);          // 8 MB
    float* hT     = (float*)alloc((size_t)N_DIM * B_DIM * 4);          // 8 MB
    int2*  packed = (int2*) alloc((size_t)E_DIM * 8);                  // 8 MB
    // shared scratch: (slab 8 MB + grp 256 KB + binTot 32 KB) vs part (8 MB) —
    // lifetimes (hist1..place2) and (gemm1..reduce1) are disjoint.
    size_t scratch_bytes = (size_t)NWG * NWORD * 4 + (size_t)NGRP * NWORD * 4 + (size_t)NWORD * 4;
    char* scratch = (char*)alloc(scratch_bytes);
    float* h1T    = (float*)alloc((size_t)H_DIM * B_DIM * 4);
    float* h2T    = (float*)alloc((size_t)H_DIM * B_DIM * 4);
    int*   offs   = (int*)  alloc((size_t)(N_DIM + 1) * 4);
    float* dinv   = (float*)alloc((size_t)N_DIM * 4);
    uint32_t* slab   = (uint32_t*)scratch;
    uint32_t* grp    = (uint32_t*)(scratch + (size_t)NWG * NWORD * 4);
    uint32_t* binTot = (uint32_t*)(scratch + (size_t)NWG * NWORD * 4 + (size_t)NGRP * NWORD * 4);
    float* part = (float*)scratch;     // SPLITK*H*B*4 = 8 MB
    if (off > ws_size) return;

    k_transpose<<<dim3(N_DIM / 32, B_DIM / 32), dim3(32, 32), 0, stream>>>(x, xT);
    k_hist1<<<NWG, 256, 0, stream>>>(dst, slab);
    k_scanA<<<NWORD * NGRP / 256, 256, 0, stream>>>(slab, grp);
    k_scanB<<<NWORD / 256, 256, 0, stream>>>(grp, binTot);
    k_scan2b<<<1, 1024, 0, stream>>>(binTot, offs);
    k_place2<<<NWG, 256, 0, stream>>>(src, dst, ew, slab, grp, offs, packed);
    k_deg<<<N_DIM, 64, 0, stream>>>(offs, packed, dinv);
    k_diffuse<<<N_DIM * NSLICE, 64, 0, stream>>>(xT, offs, packed, dinv, hT);
    k_gemm1<<<dim3(H_DIM / BM, SPLITK), 256, 0, stream>>>(W1, hT, part);
    k_reduce1<<<(H_DIM * B_DIM) / 256, 256, 0, stream>>>(part, b1, h1T);
    k_gemm2<<<H_DIM / 2, 256, 0, stream>>>(W2, b2, h1T, h2T);
    k_gemm3<<<C_DIM, 128, 0, stream>>>(Wfc, bfc, h2T, out);
}

// Round 5
// 220.248 us; speedup vs baseline: 1.2416x; 1.0699x over previous
//
#include <hip/hip_runtime.h>
#include <hip/hip_bf16.h>
#include <stdint.h>

#define B_DIM 128
#define N_DIM 16384
#define E_DIM 1048576
#define H_DIM 512
#define C_DIM 10
#define NWG 256               // wgs for hist/place
#define CHUNK (E_DIM / NWG)   // 4096 edges per wg
#define NWORD (N_DIM / 2)     // 8192 packed uint words (2 bins each)
#define NGRP 8                // scan groups
#define WPG (NWG / NGRP)      // 32 wgs per group
#define NSLICE 4              // diffusion column slices (32 cols = 2 MB each)
#define SPLITK 32
#define KC (N_DIM / SPLITK)   // 512
#define BM 64
#define KB 16

// ---------- transpose x (B,N) -> xT (N,B) ----------
__global__ void k_transpose(const float* __restrict__ x, float* __restrict__ xT) {
    __shared__ float tile[32][33];
    int bx = blockIdx.x, by = blockIdx.y;
    int tx = threadIdx.x, ty = threadIdx.y;
    int n = bx * 32 + tx, b = by * 32 + ty;
    tile[ty][tx] = x[b * N_DIM + n];
    __syncthreads();
    int n2 = bx * 32 + ty, b2 = by * 32 + tx;
    xT[n2 * B_DIM + b2] = tile[tx][ty];
}

// ---------- per-wg LDS histogram of dst (2x16-bit packed), flush to slab ----------
__global__ void __launch_bounds__(256) k_hist1(const int* __restrict__ dst,
                                               uint32_t* __restrict__ slab) {
    __shared__ uint32_t lh[NWORD];   // 32 KB
    int w = blockIdx.x, t = threadIdx.x;
#pragma unroll
    for (int i = 0; i < NWORD / 256; i++) lh[i * 256 + t] = 0;
    __syncthreads();
#pragma unroll
    for (int i = 0; i < CHUNK / 256; i++) {
        int d = dst[w * CHUNK + i * 256 + t];
        atomicAdd(&lh[d >> 1], 1u << ((d & 1) << 4));
    }
    __syncthreads();
#pragma unroll
    for (int i = 0; i < NWORD / 256; i++)
        slab[(size_t)w * NWORD + i * 256 + t] = lh[i * 256 + t];
}

// ---------- within-group (32 wgs) in-place exclusive prefix; per-group totals ----------
__global__ void __launch_bounds__(256) k_scanA(uint32_t* __restrict__ slab,
                                               uint32_t* __restrict__ grp) {
    int b = blockIdx.x;                 // 0..255
    int g = b >> 5;                     // group 0..7
    int j = (b & 31) * 256 + threadIdx.x;  // word 0..8191
    uint32_t lo = 0, hi = 0;
    for (int w = g * WPG; w < (g + 1) * WPG; w++) {
        uint32_t c = slab[(size_t)w * NWORD + j];
        slab[(size_t)w * NWORD + j] = lo | (hi << 16);
        lo += c & 0xffffu;
        hi += c >> 16;
    }
    grp[(size_t)g * NWORD + j] = lo | (hi << 16);
}

// ---------- cross-group exclusive prefix; bin totals ----------
__global__ void __launch_bounds__(256) k_scanB(uint32_t* __restrict__ grp,
                                               uint32_t* __restrict__ binTot) {
    int j = blockIdx.x * 256 + threadIdx.x;   // word 0..8191
    uint32_t lo = 0, hi = 0;
#pragma unroll
    for (int g = 0; g < NGRP; g++) {
        uint32_t c = grp[(size_t)g * NWORD + j];
        grp[(size_t)g * NWORD + j] = lo | (hi << 16);
        lo += c & 0xffffu;
        hi += c >> 16;
    }
    binTot[j] = lo | (hi << 16);
}

// ---------- single-wg exclusive scan of bin totals -> CSR offs ----------
__global__ void __launch_bounds__(1024) k_scan2b(const uint32_t* __restrict__ binTot,
                                                 int* __restrict__ offs) {
    __shared__ uint32_t part[1024];
    int t = threadIdx.x;
    uint32_t loc[16];
    uint32_t s = 0;
    int wbase = t * 8;
#pragma unroll
    for (int i = 0; i < 8; i++) {
        uint32_t wv = binTot[wbase + i];
        loc[2 * i] = s;     s += (wv & 0xffffu);
        loc[2 * i + 1] = s; s += (wv >> 16);
    }
    part[t] = s;
    __syncthreads();
    for (int off = 1; off < 1024; off <<= 1) {
        uint32_t v = (t >= off) ? part[t - off] : 0;
        __syncthreads();
        part[t] += v;
        __syncthreads();
    }
    uint32_t ex = (t == 0) ? 0 : part[t - 1];
#pragma unroll
    for (int i = 0; i < 16; i++) offs[t * 16 + i] = (int)(ex + loc[i]);
    if (t == 1023) offs[N_DIM] = (int)part[1023];
}

// ---------- atomic-free (global) placement: LDS cursor per wg ----------
__global__ void __launch_bounds__(256) k_place2(const int* __restrict__ src,
                                                const int* __restrict__ dst,
                                                const float* __restrict__ ew,
                                                const uint32_t* __restrict__ slab,
                                                const uint32_t* __restrict__ grp,
                                                const int* __restrict__ offs,
                                                int2* __restrict__ packed) {
    __shared__ uint32_t cur[N_DIM];   // 64 KB
    int w = blockIdx.x, t = threadIdx.x;
    int g = w >> 5;
#pragma unroll
    for (int i = 0; i < NWORD / 256; i++) {
        int j = i * 256 + t;
        uint32_t pv = slab[(size_t)w * NWORD + j];
        uint32_t gv = grp[(size_t)g * NWORD + j];
        int2 o = *(const int2*)&offs[2 * j];
        cur[2 * j]     = (uint32_t)o.x + (gv & 0xffffu) + (pv & 0xffffu);
        cur[2 * j + 1] = (uint32_t)o.y + (gv >> 16) + (pv >> 16);
    }
    __syncthreads();
#pragma unroll
    for (int i = 0; i < CHUNK / 256; i++) {
        int e = w * CHUNK + i * 256 + t;
        int s = src[e], d = dst[e];
        uint32_t pos = atomicAdd(&cur[d], 1u);   // LDS atomic
        packed[pos] = make_int2(s, __float_as_int(ew[e]));
    }
}

// ---------- per-node weighted in-degree from sorted segments -> dinv ----------
__global__ void __launch_bounds__(64) k_deg(const int* __restrict__ offs,
                                            const int2* __restrict__ packed,
                                            float* __restrict__ dinv) {
    int d = blockIdx.x, lane = threadIdx.x;
    int e0 = offs[d], e1 = offs[d + 1];
    float s = 0.f;
    for (int e = e0 + lane; e < e1; e += 64)
        s += __int_as_float(packed[e].y);
#pragma unroll
    for (int off = 32; off > 0; off >>= 1) s += __shfl_down(s, off);
    if (lane == 0) dinv[d] = rsqrtf(s + 1.0f);   // + self-loop weight 1; always > 0
}

// ---------- fold dinv[src]*w into packed (one coalesced pass) ----------
__global__ void k_norm(const float* __restrict__ dinv, int2* __restrict__ packed) {
    int e = blockIdx.x * 256 + threadIdx.x;
    int2 p = packed[e];
    packed[e].y = __float_as_int(__int_as_float(p.y) * dinv[p.x]);
}

// ---------- diffusion: XCD-pinned slices, register-staged edges, float4 gathers ----------
// grid = N_DIM*NSLICE; slice = bid&3 rides the round-robin block->XCD map so each
// XCD gathers only a 2 MB xT column stripe (L2-resident). 8 edge-groups x 8 lanes
// x float4 = 1 KB per gather instruction; edges broadcast from registers via shfl
// (OOB lanes stage nrm=0 -> tail is inert; no LDS, no syncthreads, no guards).
__global__ void __launch_bounds__(64) k_diffuse(const float* __restrict__ xT,
                                                const int* __restrict__ offs,
                                                const int2* __restrict__ packed,
                                                const float* __restrict__ dinv,
                                                float* __restrict__ hT) {
    int bid = blockIdx.x;
    int slice = bid & (NSLICE - 1);
    int d = bid >> 2;
    int lane = threadIdx.x;
    int g = lane >> 3;                 // edge subgroup 0..7
    int colq = slice * 8 + (lane & 7); // float4 index within row (32 per row)
    const float4* x4 = (const float4*)xT;
    float dv = dinv[d];
    float4 acc = make_float4(0.f, 0.f, 0.f, 0.f);
    if (g == 0) {
        float4 xv = x4[d * 32 + colq];
        acc.x = dv * xv.x; acc.y = dv * xv.y; acc.z = dv * xv.z; acc.w = dv * xv.w;
    }
    int e0 = offs[d], e1 = offs[d + 1];
    for (int base = e0; base < e1; base += 64) {
        int2 p = make_int2(0, 0);          // nrm=0 => inert for OOB lanes
        int e = base + lane;
        if (e < e1) p = packed[e];
#pragma unroll
        for (int i = 0; i < 64; i += 8) {
            int idx = i + g;
            int sx = __shfl(p.x, idx);
            float nm = __shfl(__int_as_float(p.y), idx);
            float4 xs = x4[sx * 32 + colq];
            acc.x = fmaf(nm, xs.x, acc.x);
            acc.y = fmaf(nm, xs.y, acc.y);
            acc.z = fmaf(nm, xs.z, acc.z);
            acc.w = fmaf(nm, xs.w, acc.w);
        }
    }
#pragma unroll
    for (int off = 8; off <= 32; off <<= 1) {
        acc.x += __shfl_xor(acc.x, off);
        acc.y += __shfl_xor(acc.y, off);
        acc.z += __shfl_xor(acc.z, off);
        acc.w += __shfl_xor(acc.w, off);
    }
    if (lane < 8) {
        acc.x *= dv; acc.y *= dv; acc.z *= dv; acc.w *= dv;
        ((float4*)hT)[d * 32 + colq] = acc;
    }
}

// ---------- GEMM1: W1(512,16384) x hT(16384,128) split-K partials ----------
__global__ void __launch_bounds__(256) k_gemm1(const float* __restrict__ W1,
                                               const float* __restrict__ hT,
                                               float* __restrict__ part) {
    int mt = blockIdx.x;   // 0..7
    int kc = blockIdx.y;   // 0..SPLITK-1
    int t = threadIdx.x;
    __shared__ float Ws[KB][BM];     // 16 x 64
    __shared__ float Hs[KB][B_DIM];  // 16 x 128
    int tn = t & 31;   // col group (*4)
    int tm = t >> 5;   // row group (*8)
    float acc[8][4];
#pragma unroll
    for (int i = 0; i < 8; i++)
#pragma unroll
        for (int j = 0; j < 4; j++) acc[i][j] = 0.f;
    int m0 = mt * BM;
    int k0 = kc * KC;
    int wr = t >> 2;         // 0..63 W row
    int wq = (t & 3) * 4;    // k quad
    int hr = t >> 4;         // 0..15 k row
    int hc = (t & 15) * 8;   // col (*8)
    for (int ks = 0; ks < KC; ks += KB) {
        float4 wv = *(const float4*)&W1[(size_t)(m0 + wr) * N_DIM + k0 + ks + wq];
        float4 h0 = *(const float4*)&hT[(k0 + ks + hr) * B_DIM + hc];
        float4 h1 = *(const float4*)&hT[(k0 + ks + hr) * B_DIM + hc + 4];
        __syncthreads();
        Ws[wq + 0][wr] = wv.x;
        Ws[wq + 1][wr] = wv.y;
        Ws[wq + 2][wr] = wv.z;
        Ws[wq + 3][wr] = wv.w;
        *(float4*)&Hs[hr][hc] = h0;
        *(float4*)&Hs[hr][hc + 4] = h1;
        __syncthreads();
#pragma unroll
        for (int kk = 0; kk < KB; kk++) {
            float a[8], b[4];
            *(float4*)&a[0] = *(const float4*)&Ws[kk][tm * 8];
            *(float4*)&a[4] = *(const float4*)&Ws[kk][tm * 8 + 4];
            *(float4*)&b[0] = *(const float4*)&Hs[kk][tn * 4];
#pragma unroll
            for (int i = 0; i < 8; i++)
#pragma unroll
                for (int j = 0; j < 4; j++)
                    acc[i][j] = fmaf(a[i], b[j], acc[i][j]);
        }
    }
    float* pbase = part + (size_t)kc * (H_DIM * B_DIM);
#pragma unroll
    for (int i = 0; i < 8; i++)
        *(float4*)&pbase[(m0 + tm * 8 + i) * B_DIM + tn * 4] = *(float4*)&acc[i][0];
}

// ---------- reduce split-K partials + bias + relu ----------
__global__ void k_reduce1(const float* __restrict__ part, const float* __restrict__ b1,
                          float* __restrict__ h1T) {
    int idx = blockIdx.x * 256 + threadIdx.x;  // 0..65535
    int j = idx >> 7;
    float s = b1[j];
#pragma unroll
    for (int c = 0; c < SPLITK; c++) s += part[c * (H_DIM * B_DIM) + idx];
    h1T[idx] = fmaxf(s, 0.f);
}

// ---------- GEMM2: W2(512,512) x h1T(512,128) + relu ----------
__global__ void __launch_bounds__(256) k_gemm2(const float* __restrict__ W2,
                                               const float* __restrict__ b2,
                                               const float* __restrict__ h1T,
                                               float* __restrict__ h2T) {
    int t = threadIdx.x;
    int b = t & 127;
    int j = blockIdx.x * 2 + (t >> 7);
    const float* wrow = W2 + j * H_DIM;
    float s = b2[j];
#pragma unroll 4
    for (int i = 0; i < H_DIM; i++)
        s = fmaf(wrow[i], h1T[i * B_DIM + b], s);
    h2T[j * B_DIM + b] = fmaxf(s, 0.f);
}

// ---------- GEMM3: Wfc(10,512) x h2T(512,128) -> out (128,10) ----------
__global__ void __launch_bounds__(128) k_gemm3(const float* __restrict__ Wfc,
                                               const float* __restrict__ bfc,
                                               const float* __restrict__ h2T,
                                               float* __restrict__ out) {
    int c = blockIdx.x;
    int b = threadIdx.x;
    const float* wrow = Wfc + c * H_DIM;
    float s = bfc[c];
#pragma unroll 4
    for (int i = 0; i < H_DIM; i++)
        s = fmaf(wrow[i], h2T[i * B_DIM + b], s);
    out[b * C_DIM + c] = s;
}

extern "C" void kernel_launch(void* const* d_in, const int* in_sizes, int n_in,
                              void* d_out, int out_size, void* d_ws, size_t ws_size,
                              hipStream_t stream) {
    const float* x   = (const float*)d_in[0];
    const int*   ei  = (const int*)d_in[1];
    const float* ew  = (const float*)d_in[2];
    const float* W1  = (const float*)d_in[3];
    const float* b1  = (const float*)d_in[4];
    const float* W2  = (const float*)d_in[5];
    const float* b2  = (const float*)d_in[6];
    const float* Wfc = (const float*)d_in[7];
    const float* bfc = (const float*)d_in[8];
    float* out = (float*)d_out;

    const int* src = ei;
    const int* dst = ei + E_DIM;

    char* ws = (char*)d_ws;
    size_t off = 0;
    auto alloc = [&](size_t bytes) -> void* {
        void* p = ws + off;
        off = (off + bytes + 255) & ~(size_t)255;
        return p;
    };
    float* xT     = (float*)alloc((size_t)N_DIM * B_DIM * 4);          // 8 MB
    float* hT     = (float*)alloc((size_t)N_DIM * B_DIM * 4);          // 8 MB
    int2*  packed = (int2*) alloc((size_t)E_DIM * 8);                  // 8 MB
    // shared scratch: (slab 8 MB + grp 256 KB + binTot 32 KB) vs part (8 MB) —
    // lifetimes (hist1..place2) and (gemm1..reduce1) are disjoint.
    size_t scratch_bytes = (size_t)NWG * NWORD * 4 + (size_t)NGRP * NWORD * 4 + (size_t)NWORD * 4;
    char* scratch = (char*)alloc(scratch_bytes);
    float* h1T    = (float*)alloc((size_t)H_DIM * B_DIM * 4);
    float* h2T    = (float*)alloc((size_t)H_DIM * B_DIM * 4);
    int*   offs   = (int*)  alloc((size_t)(N_DIM + 1) * 4);
    float* dinv   = (float*)alloc((size_t)N_DIM * 4);
    uint32_t* slab   = (uint32_t*)scratch;
    uint32_t* grp    = (uint32_t*)(scratch + (size_t)NWG * NWORD * 4);
    uint32_t* binTot = (uint32_t*)(scratch + (size_t)NWG * NWORD * 4 + (size_t)NGRP * NWORD * 4);
    float* part = (float*)scratch;     // SPLITK*H*B*4 = 8 MB
    if (off > ws_size) return;

    k_transpose<<<dim3(N_DIM / 32, B_DIM / 32), dim3(32, 32), 0, stream>>>(x, xT);
    k_hist1<<<NWG, 256, 0, stream>>>(dst, slab);
    k_scanA<<<NWORD * NGRP / 256, 256, 0, stream>>>(slab, grp);
    k_scanB<<<NWORD / 256, 256, 0, stream>>>(grp, binTot);
    k_scan2b<<<1, 1024, 0, stream>>>(binTot, offs);
    k_place2<<<NWG, 256, 0, stream>>>(src, dst, ew, slab, grp, offs, packed);
    k_deg<<<N_DIM, 64, 0, stream>>>(offs, packed, dinv);
    k_norm<<<E_DIM / 256, 256, 0, stream>>>(dinv, packed);
    k_diffuse<<<N_DIM * NSLICE, 64, 0, stream>>>(xT, offs, packed, dinv, hT);
    k_gemm1<<<dim3(H_DIM / BM, SPLITK), 256, 0, stream>>>(W1, hT, part);
    k_reduce1<<<(H_DIM * B_DIM) / 256, 256, 0, stream>>>(part, b1, h1T);
    k_gemm2<<<H_DIM / 2, 256, 0, stream>>>(W2, b2, h1T, h2T);
    k_gemm3<<<C_DIM, 128, 0, stream>>>(Wfc, bfc, h2T, out);
}

// Round 6
// 219.786 us; speedup vs baseline: 1.2442x; 1.0021x over previous
//
#include <hip/hip_runtime.h>
#include <hip/hip_bf16.h>
#include <stdint.h>

#define B_DIM 128
#define N_DIM 16384
#define E_DIM 1048576
#define H_DIM 512
#define C_DIM 10
#define NWG 256               // wgs for hist/place
#define CHUNK (E_DIM / NWG)   // 4096 edges per wg
#define NWORD (N_DIM / 2)     // 8192 packed uint words (2 bins each)
#define NGRP 8                // scan groups
#define WPG (NWG / NGRP)      // 32 wgs per group
#define NSLICE 4              // diffusion column slices (32 cols = 2 MB each)
#define SPLITK 64
#define KC (N_DIM / SPLITK)   // 256
#define BM 64
#define KB 16

// ---------- transpose x (B,N) -> xT (N,B) ----------
__global__ void k_transpose(const float* __restrict__ x, float* __restrict__ xT) {
    __shared__ float tile[32][33];
    int bx = blockIdx.x, by = blockIdx.y;
    int tx = threadIdx.x, ty = threadIdx.y;
    int n = bx * 32 + tx, b = by * 32 + ty;
    tile[ty][tx] = x[b * N_DIM + n];
    __syncthreads();
    int n2 = bx * 32 + ty, b2 = by * 32 + tx;
    xT[n2 * B_DIM + b2] = tile[tx][ty];
}

// ---------- per-wg LDS histogram of dst (2x16-bit packed), flush to slab ----------
__global__ void __launch_bounds__(256) k_hist1(const int* __restrict__ dst,
                                               uint32_t* __restrict__ slab) {
    __shared__ uint32_t lh[NWORD];   // 32 KB
    int w = blockIdx.x, t = threadIdx.x;
#pragma unroll
    for (int i = 0; i < NWORD / 256; i++) lh[i * 256 + t] = 0;
    __syncthreads();
#pragma unroll
    for (int i = 0; i < CHUNK / 256; i++) {
        int d = dst[w * CHUNK + i * 256 + t];
        atomicAdd(&lh[d >> 1], 1u << ((d & 1) << 4));
    }
    __syncthreads();
#pragma unroll
    for (int i = 0; i < NWORD / 256; i++)
        slab[(size_t)w * NWORD + i * 256 + t] = lh[i * 256 + t];
}

// ---------- within-group (32 wgs) in-place exclusive prefix; per-group totals ----------
__global__ void __launch_bounds__(256) k_scanA(uint32_t* __restrict__ slab,
                                               uint32_t* __restrict__ grp) {
    int b = blockIdx.x;                 // 0..255
    int g = b >> 5;                     // group 0..7
    int j = (b & 31) * 256 + threadIdx.x;  // word 0..8191
    uint32_t lo = 0, hi = 0;
    for (int w = g * WPG; w < (g + 1) * WPG; w++) {
        uint32_t c = slab[(size_t)w * NWORD + j];
        slab[(size_t)w * NWORD + j] = lo | (hi << 16);
        lo += c & 0xffffu;
        hi += c >> 16;
    }
    grp[(size_t)g * NWORD + j] = lo | (hi << 16);
}

// ---------- cross-group exclusive prefix; bin totals ----------
__global__ void __launch_bounds__(256) k_scanB(uint32_t* __restrict__ grp,
                                               uint32_t* __restrict__ binTot) {
    int j = blockIdx.x * 256 + threadIdx.x;   // word 0..8191
    uint32_t lo = 0, hi = 0;
#pragma unroll
    for (int g = 0; g < NGRP; g++) {
        uint32_t c = grp[(size_t)g * NWORD + j];
        grp[(size_t)g * NWORD + j] = lo | (hi << 16);
        lo += c & 0xffffu;
        hi += c >> 16;
    }
    binTot[j] = lo | (hi << 16);
}

// ---------- single-wg exclusive scan of bin totals -> CSR offs ----------
__global__ void __launch_bounds__(1024) k_scan2b(const uint32_t* __restrict__ binTot,
                                                 int* __restrict__ offs) {
    __shared__ uint32_t part[1024];
    int t = threadIdx.x;
    uint32_t loc[16];
    uint32_t s = 0;
    int wbase = t * 8;
#pragma unroll
    for (int i = 0; i < 8; i++) {
        uint32_t wv = binTot[wbase + i];
        loc[2 * i] = s;     s += (wv & 0xffffu);
        loc[2 * i + 1] = s; s += (wv >> 16);
    }
    part[t] = s;
    __syncthreads();
    for (int off = 1; off < 1024; off <<= 1) {
        uint32_t v = (t >= off) ? part[t - off] : 0;
        __syncthreads();
        part[t] += v;
        __syncthreads();
    }
    uint32_t ex = (t == 0) ? 0 : part[t - 1];
#pragma unroll
    for (int i = 0; i < 16; i++) offs[t * 16 + i] = (int)(ex + loc[i]);
    if (t == 1023) offs[N_DIM] = (int)part[1023];
}

// ---------- atomic-free (global) placement: LDS cursor per wg ----------
__global__ void __launch_bounds__(256) k_place2(const int* __restrict__ src,
                                                const int* __restrict__ dst,
                                                const float* __restrict__ ew,
                                                const uint32_t* __restrict__ slab,
                                                const uint32_t* __restrict__ grp,
                                                const int* __restrict__ offs,
                                                int2* __restrict__ packed) {
    __shared__ uint32_t cur[N_DIM];   // 64 KB
    int w = blockIdx.x, t = threadIdx.x;
    int g = w >> 5;
#pragma unroll
    for (int i = 0; i < NWORD / 256; i++) {
        int j = i * 256 + t;
        uint32_t pv = slab[(size_t)w * NWORD + j];
        uint32_t gv = grp[(size_t)g * NWORD + j];
        int2 o = *(const int2*)&offs[2 * j];
        cur[2 * j]     = (uint32_t)o.x + (gv & 0xffffu) + (pv & 0xffffu);
        cur[2 * j + 1] = (uint32_t)o.y + (gv >> 16) + (pv >> 16);
    }
    __syncthreads();
#pragma unroll
    for (int i = 0; i < CHUNK / 256; i++) {
        int e = w * CHUNK + i * 256 + t;
        int s = src[e], d = dst[e];
        uint32_t pos = atomicAdd(&cur[d], 1u);   // LDS atomic
        packed[pos] = make_int2(s, __float_as_int(ew[e]));
    }
}

// ---------- per-node weighted in-degree from sorted segments -> dinv ----------
__global__ void __launch_bounds__(64) k_deg(const int* __restrict__ offs,
                                            const int2* __restrict__ packed,
                                            float* __restrict__ dinv) {
    int d = blockIdx.x, lane = threadIdx.x;
    int e0 = offs[d], e1 = offs[d + 1];
    float s = 0.f;
    for (int e = e0 + lane; e < e1; e += 64)
        s += __int_as_float(packed[e].y);
#pragma unroll
    for (int off = 32; off > 0; off >>= 1) s += __shfl_down(s, off);
    if (lane == 0) dinv[d] = rsqrtf(s + 1.0f);   // + self-loop weight 1; always > 0
}

// ---------- fold dinv[src]*w into packed (one coalesced pass) ----------
__global__ void k_norm(const float* __restrict__ dinv, int2* __restrict__ packed) {
    int e = blockIdx.x * 256 + threadIdx.x;
    int2 p = packed[e];
    packed[e].y = __float_as_int(__int_as_float(p.y) * dinv[p.x]);
}

// ---------- diffusion: XCD-pinned slices, register-staged edges, float4 gathers ----------
__global__ void __launch_bounds__(64) k_diffuse(const float* __restrict__ xT,
                                                const int* __restrict__ offs,
                                                const int2* __restrict__ packed,
                                                const float* __restrict__ dinv,
                                                float* __restrict__ hT) {
    int bid = blockIdx.x;
    int slice = bid & (NSLICE - 1);
    int d = bid >> 2;
    int lane = threadIdx.x;
    int g = lane >> 3;                 // edge subgroup 0..7
    int colq = slice * 8 + (lane & 7); // float4 index within row (32 per row)
    const float4* x4 = (const float4*)xT;
    float dv = dinv[d];
    float4 acc = make_float4(0.f, 0.f, 0.f, 0.f);
    if (g == 0) {
        float4 xv = x4[d * 32 + colq];
        acc.x = dv * xv.x; acc.y = dv * xv.y; acc.z = dv * xv.z; acc.w = dv * xv.w;
    }
    int e0 = offs[d], e1 = offs[d + 1];
    for (int base = e0; base < e1; base += 64) {
        int2 p = make_int2(0, 0);          // nrm=0 => inert for OOB lanes
        int e = base + lane;
        if (e < e1) p = packed[e];
#pragma unroll
        for (int i = 0; i < 64; i += 8) {
            int idx = i + g;
            int sx = __shfl(p.x, idx);
            float nm = __shfl(__int_as_float(p.y), idx);
            float4 xs = x4[sx * 32 + colq];
            acc.x = fmaf(nm, xs.x, acc.x);
            acc.y = fmaf(nm, xs.y, acc.y);
            acc.z = fmaf(nm, xs.z, acc.z);
            acc.w = fmaf(nm, xs.w, acc.w);
        }
    }
#pragma unroll
    for (int off = 8; off <= 32; off <<= 1) {
        acc.x += __shfl_xor(acc.x, off);
        acc.y += __shfl_xor(acc.y, off);
        acc.z += __shfl_xor(acc.z, off);
        acc.w += __shfl_xor(acc.w, off);
    }
    if (lane < 8) {
        acc.x *= dv; acc.y *= dv; acc.z *= dv; acc.w *= dv;
        ((float4*)hT)[d * 32 + colq] = acc;
    }
}

// ---------- GEMM1: W1(512,16384) x hT(16384,128) split-K partials ----------
// grid(x=kc, y=mt): same-kc blocks (sharing a 128 KB hT slice) have linear id
// == kc (mod 8) -> same XCD -> hT re-reads are L2 hits. W1 is fully partitioned.
// Double-buffered LDS, ONE barrier per K-tile: store->sync->(prefetch || compute).
__global__ void __launch_bounds__(256) k_gemm1(const float* __restrict__ W1,
                                               const float* __restrict__ hT,
                                               float* __restrict__ part) {
    int kc = blockIdx.x;   // 0..SPLITK-1
    int mt = blockIdx.y;   // 0..7
    int t = threadIdx.x;
    __shared__ float Ws[2][KB][BM + 4];      // 16B-aligned rows (68*4=272)
    __shared__ float Hs[2][KB][B_DIM + 4];   // (132*4=528)
    int tn = t & 31;   // col group (*4)
    int tm = t >> 5;   // row group (*8)
    float acc[8][4];
#pragma unroll
    for (int i = 0; i < 8; i++)
#pragma unroll
        for (int j = 0; j < 4; j++) acc[i][j] = 0.f;
    int m0 = mt * BM;
    int k0 = kc * KC;
    int wr = t >> 2;         // 0..63 W row
    int wq = (t & 3) * 4;    // k quad
    int hr = t >> 4;         // 0..15 k row
    int hc = (t & 15) * 8;   // col (*8)
    const float* wp = &W1[(size_t)(m0 + wr) * N_DIM + k0 + wq];
    const float* hp = &hT[(size_t)(k0 + hr) * B_DIM + hc];
    float4 wv = *(const float4*)wp;
    float4 h0 = *(const float4*)hp;
    float4 h1 = *(const float4*)(hp + 4);
    for (int ks = 0; ks < KC; ks += KB) {
        int buf = (ks >> 4) & 1;
        Ws[buf][wq + 0][wr] = wv.x;
        Ws[buf][wq + 1][wr] = wv.y;
        Ws[buf][wq + 2][wr] = wv.z;
        Ws[buf][wq + 3][wr] = wv.w;
        *(float4*)&Hs[buf][hr][hc] = h0;
        *(float4*)&Hs[buf][hr][hc + 4] = h1;
        __syncthreads();
        if (ks + KB < KC) {   // prefetch next tile while computing this one
            wv = *(const float4*)(wp + ks + KB);
            h0 = *(const float4*)(hp + (size_t)(ks + KB) * B_DIM);
            h1 = *(const float4*)(hp + (size_t)(ks + KB) * B_DIM + 4);
        }
#pragma unroll
        for (int kk = 0; kk < KB; kk++) {
            float a[8], b[4];
            *(float4*)&a[0] = *(const float4*)&Ws[buf][kk][tm * 8];
            *(float4*)&a[4] = *(const float4*)&Ws[buf][kk][tm * 8 + 4];
            *(float4*)&b[0] = *(const float4*)&Hs[buf][kk][tn * 4];
#pragma unroll
            for (int i = 0; i < 8; i++)
#pragma unroll
                for (int j = 0; j < 4; j++)
                    acc[i][j] = fmaf(a[i], b[j], acc[i][j]);
        }
        // no second barrier: next iter stores to buf^1, whose readers finished
        // before the barrier above (2-buffer rotation argument)
    }
    float* pbase = part + (size_t)kc * (H_DIM * B_DIM);
#pragma unroll
    for (int i = 0; i < 8; i++)
        *(float4*)&pbase[(size_t)(m0 + tm * 8 + i) * B_DIM + tn * 4] = *(float4*)&acc[i][0];
}

// ---------- reduce split-K partials + bias + relu ----------
__global__ void k_reduce1(const float* __restrict__ part, const float* __restrict__ b1,
                          float* __restrict__ h1T) {
    int idx = blockIdx.x * 256 + threadIdx.x;  // 0..65535
    int j = idx >> 7;
    float s = b1[j];
#pragma unroll
    for (int c = 0; c < SPLITK; c++) s += part[c * (H_DIM * B_DIM) + idx];
    h1T[idx] = fmaxf(s, 0.f);
}

// ---------- GEMM2: W2(512,512) x h1T(512,128) + relu ----------
__global__ void __launch_bounds__(256) k_gemm2(const float* __restrict__ W2,
                                               const float* __restrict__ b2,
                                               const float* __restrict__ h1T,
                                               float* __restrict__ h2T) {
    int t = threadIdx.x;
    int b = t & 127;
    int j = blockIdx.x * 2 + (t >> 7);
    const float* wrow = W2 + j * H_DIM;
    float s = b2[j];
#pragma unroll 4
    for (int i = 0; i < H_DIM; i++)
        s = fmaf(wrow[i], h1T[i * B_DIM + b], s);
    h2T[j * B_DIM + b] = fmaxf(s, 0.f);
}

// ---------- GEMM3: Wfc(10,512) x h2T(512,128) -> out (128,10) ----------
__global__ void __launch_bounds__(128) k_gemm3(const float* __restrict__ Wfc,
                                               const float* __restrict__ bfc,
                                               const float* __restrict__ h2T,
                                               float* __restrict__ out) {
    int c = blockIdx.x;
    int b = threadIdx.x;
    const float* wrow = Wfc + c * H_DIM;
    float s = bfc[c];
#pragma unroll 4
    for (int i = 0; i < H_DIM; i++)
        s = fmaf(wrow[i], h2T[i * B_DIM + b], s);
    out[b * C_DIM + c] = s;
}

extern "C" void kernel_launch(void* const* d_in, const int* in_sizes, int n_in,
                              void* d_out, int out_size, void* d_ws, size_t ws_size,
                              hipStream_t stream) {
    const float* x   = (const float*)d_in[0];
    const int*   ei  = (const int*)d_in[1];
    const float* ew  = (const float*)d_in[2];
    const float* W1  = (const float*)d_in[3];
    const float* b1  = (const float*)d_in[4];
    const float* W2  = (const float*)d_in[5];
    const float* b2  = (const float*)d_in[6];
    const float* Wfc = (const float*)d_in[7];
    const float* bfc = (const float*)d_in[8];
    float* out = (float*)d_out;

    const int* src = ei;
    const int* dst = ei + E_DIM;

    char* ws = (char*)d_ws;
    size_t off = 0;
    auto alloc = [&](size_t bytes) -> void* {
        void* p = ws + off;
        off = (off + bytes + 255) & ~(size_t)255;
        return p;
    };
    float* xT     = (float*)alloc((size_t)N_DIM * B_DIM * 4);          // 8 MB
    float* hT     = (float*)alloc((size_t)N_DIM * B_DIM * 4);          // 8 MB
    int2*  packed = (int2*) alloc((size_t)E_DIM * 8);                  // 8 MB
    // shared scratch: union of (slab 8 MB + grp 256 KB + binTot 32 KB) and
    // part (16 MB) — lifetimes (hist1..place2) vs (gemm1..reduce1) disjoint.
    size_t sort_bytes = (size_t)NWG * NWORD * 4 + (size_t)NGRP * NWORD * 4 + (size_t)NWORD * 4;
    size_t part_bytes = (size_t)SPLITK * H_DIM * B_DIM * 4;
    char* scratch = (char*)alloc(sort_bytes > part_bytes ? sort_bytes : part_bytes);
    float* h1T    = (float*)alloc((size_t)H_DIM * B_DIM * 4);
    float* h2T    = (float*)alloc((size_t)H_DIM * B_DIM * 4);
    int*   offs   = (int*)  alloc((size_t)(N_DIM + 1) * 4);
    float* dinv   = (float*)alloc((size_t)N_DIM * 4);
    uint32_t* slab   = (uint32_t*)scratch;
    uint32_t* grp    = (uint32_t*)(scratch + (size_t)NWG * NWORD * 4);
    uint32_t* binTot = (uint32_t*)(scratch + (size_t)NWG * NWORD * 4 + (size_t)NGRP * NWORD * 4);
    float* part = (float*)scratch;
    if (off > ws_size) return;

    k_transpose<<<dim3(N_DIM / 32, B_DIM / 32), dim3(32, 32), 0, stream>>>(x, xT);
    k_hist1<<<NWG, 256, 0, stream>>>(dst, slab);
    k_scanA<<<NWORD * NGRP / 256, 256, 0, stream>>>(slab, grp);
    k_scanB<<<NWORD / 256, 256, 0, stream>>>(grp, binTot);
    k_scan2b<<<1, 1024, 0, stream>>>(binTot, offs);
    k_place2<<<NWG, 256, 0, stream>>>(src, dst, ew, slab, grp, offs, packed);
    k_deg<<<N_DIM, 64, 0, stream>>>(offs, packed, dinv);
    k_norm<<<E_DIM / 256, 256, 0, stream>>>(dinv, packed);
    k_diffuse<<<N_DIM * NSLICE, 64, 0, stream>>>(xT, offs, packed, dinv, hT);
    k_gemm1<<<dim3(SPLITK, H_DIM / BM), 256, 0, stream>>>(W1, hT, part);
    k_reduce1<<<(H_DIM * B_DIM) / 256, 256, 0, stream>>>(part, b1, h1T);
    k_gemm2<<<H_DIM / 2, 256, 0, stream>>>(W2, b2, h1T, h2T);
    k_gemm3<<<C_DIM, 128, 0, stream>>>(Wfc, bfc, h2T, out);
}

// Round 7
// 161.373 us; speedup vs baseline: 1.6945x; 1.3620x over previous
//
#include <hip/hip_runtime.h>
#include <hip/hip_bf16.h>
#include <stdint.h>

#define B_DIM 128
#define N_DIM 16384
#define E_DIM 1048576
#define H_DIM 512
#define C_DIM 10
#define NWG 256               // wgs for hist/place
#define CHUNK (E_DIM / NWG)   // 4096 edges per wg
#define NWORD (N_DIM / 2)     // 8192 packed uint words (2 bins each)
#define NGRP 8                // scan groups
#define WPG (NWG / NGRP)      // 32 wgs per group
#define NSLICE 4              // diffusion column slices (32 cols = 2 MB each)
#define SPLITK 64
#define KC (N_DIM / SPLITK)   // 256
#define BM 64
#define KB 16

// ---------- transpose x (B,N) -> xT (N,B) ----------
__global__ void k_transpose(const float* __restrict__ x, float* __restrict__ xT) {
    __shared__ float tile[32][33];
    int bx = blockIdx.x, by = blockIdx.y;
    int tx = threadIdx.x, ty = threadIdx.y;
    int n = bx * 32 + tx, b = by * 32 + ty;
    tile[ty][tx] = x[b * N_DIM + n];
    __syncthreads();
    int n2 = bx * 32 + ty, b2 = by * 32 + tx;
    xT[n2 * B_DIM + b2] = tile[tx][ty];
}

// ---------- per-wg LDS histogram of dst (2x16-bit packed), flush to slab ----------
__global__ void __launch_bounds__(256) k_hist1(const int* __restrict__ dst,
                                               uint32_t* __restrict__ slab) {
    __shared__ uint32_t lh[NWORD];   // 32 KB
    int w = blockIdx.x, t = threadIdx.x;
#pragma unroll
    for (int i = 0; i < NWORD / 256; i++) lh[i * 256 + t] = 0;
    __syncthreads();
#pragma unroll
    for (int i = 0; i < CHUNK / 256; i++) {
        int d = dst[w * CHUNK + i * 256 + t];
        atomicAdd(&lh[d >> 1], 1u << ((d & 1) << 4));
    }
    __syncthreads();
#pragma unroll
    for (int i = 0; i < NWORD / 256; i++)
        slab[(size_t)w * NWORD + i * 256 + t] = lh[i * 256 + t];
}

// ---------- within-group (32 wgs) in-place exclusive prefix; per-group totals ----------
__global__ void __launch_bounds__(256) k_scanA(uint32_t* __restrict__ slab,
                                               uint32_t* __restrict__ grp) {
    int b = blockIdx.x;                 // 0..255
    int g = b >> 5;                     // group 0..7
    int j = (b & 31) * 256 + threadIdx.x;  // word 0..8191
    uint32_t lo = 0, hi = 0;
    for (int w = g * WPG; w < (g + 1) * WPG; w++) {
        uint32_t c = slab[(size_t)w * NWORD + j];
        slab[(size_t)w * NWORD + j] = lo | (hi << 16);
        lo += c & 0xffffu;
        hi += c >> 16;
    }
    grp[(size_t)g * NWORD + j] = lo | (hi << 16);
}

// ---------- cross-group exclusive prefix; bin totals ----------
__global__ void __launch_bounds__(256) k_scanB(uint32_t* __restrict__ grp,
                                               uint32_t* __restrict__ binTot) {
    int j = blockIdx.x * 256 + threadIdx.x;   // word 0..8191
    uint32_t lo = 0, hi = 0;
#pragma unroll
    for (int g = 0; g < NGRP; g++) {
        uint32_t c = grp[(size_t)g * NWORD + j];
        grp[(size_t)g * NWORD + j] = lo | (hi << 16);
        lo += c & 0xffffu;
        hi += c >> 16;
    }
    binTot[j] = lo | (hi << 16);
}

// ---------- single-wg exclusive scan of bin totals -> CSR offs ----------
__global__ void __launch_bounds__(1024) k_scan2b(const uint32_t* __restrict__ binTot,
                                                 int* __restrict__ offs) {
    __shared__ uint32_t part[1024];
    int t = threadIdx.x;
    uint32_t loc[16];
    uint32_t s = 0;
    int wbase = t * 8;
#pragma unroll
    for (int i = 0; i < 8; i++) {
        uint32_t wv = binTot[wbase + i];
        loc[2 * i] = s;     s += (wv & 0xffffu);
        loc[2 * i + 1] = s; s += (wv >> 16);
    }
    part[t] = s;
    __syncthreads();
    for (int off = 1; off < 1024; off <<= 1) {
        uint32_t v = (t >= off) ? part[t - off] : 0;
        __syncthreads();
        part[t] += v;
        __syncthreads();
    }
    uint32_t ex = (t == 0) ? 0 : part[t - 1];
#pragma unroll
    for (int i = 0; i < 16; i++) offs[t * 16 + i] = (int)(ex + loc[i]);
    if (t == 1023) offs[N_DIM] = (int)part[1023];
}

// ---------- atomic-free (global) placement: LDS cursor per wg ----------
__global__ void __launch_bounds__(256) k_place2(const int* __restrict__ src,
                                                const int* __restrict__ dst,
                                                const float* __restrict__ ew,
                                                const uint32_t* __restrict__ slab,
                                                const uint32_t* __restrict__ grp,
                                                const int* __restrict__ offs,
                                                int2* __restrict__ packed) {
    __shared__ uint32_t cur[N_DIM];   // 64 KB
    int w = blockIdx.x, t = threadIdx.x;
    int g = w >> 5;
#pragma unroll
    for (int i = 0; i < NWORD / 256; i++) {
        int j = i * 256 + t;
        uint32_t pv = slab[(size_t)w * NWORD + j];
        uint32_t gv = grp[(size_t)g * NWORD + j];
        int2 o = *(const int2*)&offs[2 * j];
        cur[2 * j]     = (uint32_t)o.x + (gv & 0xffffu) + (pv & 0xffffu);
        cur[2 * j + 1] = (uint32_t)o.y + (gv >> 16) + (pv >> 16);
    }
    __syncthreads();
#pragma unroll
    for (int i = 0; i < CHUNK / 256; i++) {
        int e = w * CHUNK + i * 256 + t;
        int s = src[e], d = dst[e];
        uint32_t pos = atomicAdd(&cur[d], 1u);   // LDS atomic
        packed[pos] = make_int2(s, __float_as_int(ew[e]));
    }
}

// ---------- per-node weighted in-degree from sorted segments -> dinv ----------
__global__ void __launch_bounds__(64) k_deg(const int* __restrict__ offs,
                                            const int2* __restrict__ packed,
                                            float* __restrict__ dinv) {
    int d = blockIdx.x, lane = threadIdx.x;
    int e0 = offs[d], e1 = offs[d + 1];
    float s = 0.f;
    for (int e = e0 + lane; e < e1; e += 64)
        s += __int_as_float(packed[e].y);
#pragma unroll
    for (int off = 32; off > 0; off >>= 1) s += __shfl_down(s, off);
    if (lane == 0) dinv[d] = rsqrtf(s + 1.0f);   // + self-loop weight 1; always > 0
}

// ---------- fold dinv[src]*w into packed (one coalesced pass) ----------
__global__ void k_norm(const float* __restrict__ dinv, int2* __restrict__ packed) {
    int e = blockIdx.x * 256 + threadIdx.x;
    int2 p = packed[e];
    packed[e].y = __float_as_int(__int_as_float(p.y) * dinv[p.x]);
}

// ---------- diffusion: XCD-pinned slices, register-staged edges, float4 gathers ----------
__global__ void __launch_bounds__(64) k_diffuse(const float* __restrict__ xT,
                                                const int* __restrict__ offs,
                                                const int2* __restrict__ packed,
                                                const float* __restrict__ dinv,
                                                float* __restrict__ hT) {
    int bid = blockIdx.x;
    int slice = bid & (NSLICE - 1);
    int d = bid >> 2;
    int lane = threadIdx.x;
    int g = lane >> 3;                 // edge subgroup 0..7
    int colq = slice * 8 + (lane & 7); // float4 index within row (32 per row)
    const float4* x4 = (const float4*)xT;
    float dv = dinv[d];
    float4 acc = make_float4(0.f, 0.f, 0.f, 0.f);
    if (g == 0) {
        float4 xv = x4[d * 32 + colq];
        acc.x = dv * xv.x; acc.y = dv * xv.y; acc.z = dv * xv.z; acc.w = dv * xv.w;
    }
    int e0 = offs[d], e1 = offs[d + 1];
    for (int base = e0; base < e1; base += 64) {
        int2 p = make_int2(0, 0);          // nrm=0 => inert for OOB lanes
        int e = base + lane;
        if (e < e1) p = packed[e];
#pragma unroll
        for (int i = 0; i < 64; i += 8) {
            int idx = i + g;
            int sx = __shfl(p.x, idx);
            float nm = __shfl(__int_as_float(p.y), idx);
            float4 xs = x4[sx * 32 + colq];
            acc.x = fmaf(nm, xs.x, acc.x);
            acc.y = fmaf(nm, xs.y, acc.y);
            acc.z = fmaf(nm, xs.z, acc.z);
            acc.w = fmaf(nm, xs.w, acc.w);
        }
    }
#pragma unroll
    for (int off = 8; off <= 32; off <<= 1) {
        acc.x += __shfl_xor(acc.x, off);
        acc.y += __shfl_xor(acc.y, off);
        acc.z += __shfl_xor(acc.z, off);
        acc.w += __shfl_xor(acc.w, off);
    }
    if (lane < 8) {
        acc.x *= dv; acc.y *= dv; acc.z *= dv; acc.w *= dv;
        ((float4*)hT)[d * 32 + colq] = acc;
    }
}

// ---------- GEMM1: W1(512,16384) x hT(16384,128) split-K partials ----------
__global__ void __launch_bounds__(256) k_gemm1(const float* __restrict__ W1,
                                               const float* __restrict__ hT,
                                               float* __restrict__ part) {
    int kc = blockIdx.x;   // 0..SPLITK-1
    int mt = blockIdx.y;   // 0..7
    int t = threadIdx.x;
    __shared__ float Ws[2][KB][BM + 4];
    __shared__ float Hs[2][KB][B_DIM + 4];
    int tn = t & 31;   // col group (*4)
    int tm = t >> 5;   // row group (*8)
    float acc[8][4];
#pragma unroll
    for (int i = 0; i < 8; i++)
#pragma unroll
        for (int j = 0; j < 4; j++) acc[i][j] = 0.f;
    int m0 = mt * BM;
    int k0 = kc * KC;
    int wr = t >> 2;         // 0..63 W row
    int wq = (t & 3) * 4;    // k quad
    int hr = t >> 4;         // 0..15 k row
    int hc = (t & 15) * 8;   // col (*8)
    const float* wp = &W1[(size_t)(m0 + wr) * N_DIM + k0 + wq];
    const float* hp = &hT[(size_t)(k0 + hr) * B_DIM + hc];
    float4 wv = *(const float4*)wp;
    float4 h0 = *(const float4*)hp;
    float4 h1 = *(const float4*)(hp + 4);
    for (int ks = 0; ks < KC; ks += KB) {
        int buf = (ks >> 4) & 1;
        Ws[buf][wq + 0][wr] = wv.x;
        Ws[buf][wq + 1][wr] = wv.y;
        Ws[buf][wq + 2][wr] = wv.z;
        Ws[buf][wq + 3][wr] = wv.w;
        *(float4*)&Hs[buf][hr][hc] = h0;
        *(float4*)&Hs[buf][hr][hc + 4] = h1;
        __syncthreads();
        if (ks + KB < KC) {   // prefetch next tile while computing this one
            wv = *(const float4*)(wp + ks + KB);
            h0 = *(const float4*)(hp + (size_t)(ks + KB) * B_DIM);
            h1 = *(const float4*)(hp + (size_t)(ks + KB) * B_DIM + 4);
        }
#pragma unroll
        for (int kk = 0; kk < KB; kk++) {
            float a[8], b[4];
            *(float4*)&a[0] = *(const float4*)&Ws[buf][kk][tm * 8];
            *(float4*)&a[4] = *(const float4*)&Ws[buf][kk][tm * 8 + 4];
            *(float4*)&b[0] = *(const float4*)&Hs[buf][kk][tn * 4];
#pragma unroll
            for (int i = 0; i < 8; i++)
#pragma unroll
                for (int j = 0; j < 4; j++)
                    acc[i][j] = fmaf(a[i], b[j], acc[i][j]);
        }
    }
    float* pbase = part + (size_t)kc * (H_DIM * B_DIM);
#pragma unroll
    for (int i = 0; i < 8; i++)
        *(float4*)&pbase[(size_t)(m0 + tm * 8 + i) * B_DIM + tn * 4] = *(float4*)&acc[i][0];
}

// ---------- reduce split-K partials + bias + relu -> h1[b][j] ----------
__global__ void k_reduce1(const float* __restrict__ part, const float* __restrict__ b1,
                          float* __restrict__ h1) {
    int idx = blockIdx.x * 256 + threadIdx.x;  // 0..65535 (j*128+b)
    int j = idx >> 7;
    int b = idx & 127;
    float s = b1[j];
#pragma unroll
    for (int c = 0; c < SPLITK; c++) s += part[c * (H_DIM * B_DIM) + idx];
    h1[b * H_DIM + j] = fmaxf(s, 0.f);   // transposed write -> [b][j]
}

// ---------- GEMM2 (K-parallel): one wave per (b, 8 hidden units) ----------
// h2[b][j] = relu(b2[j] + sum_i W2[j][i]*h1[b][i]); lanes span K, butterfly reduce.
__global__ void __launch_bounds__(256) k_gemm2(const float* __restrict__ W2,
                                               const float* __restrict__ b2,
                                               const float* __restrict__ h1,
                                               float* __restrict__ h2) {
    int w = blockIdx.x * 4 + (threadIdx.x >> 6);   // wave 0..8191
    int l = threadIdx.x & 63;
    int b = w >> 6;            // 0..127
    int j0 = (w & 63) * 8;     // 0..511 step 8
    const float* hb = h1 + (size_t)b * H_DIM;
    float hv[8];
#pragma unroll
    for (int k = 0; k < 8; k++) hv[k] = hb[k * 64 + l];
    float outv = 0.f;
#pragma unroll
    for (int jj = 0; jj < 8; jj++) {
        const float* wrow = W2 + (size_t)(j0 + jj) * H_DIM;
        float a = 0.f;
#pragma unroll
        for (int k = 0; k < 8; k++) a = fmaf(wrow[k * 64 + l], hv[k], a);
#pragma unroll
        for (int o = 1; o < 64; o <<= 1) a += __shfl_xor(a, o);
        if (l == jj) outv = a;
    }
    if (l < 8) h2[(size_t)b * H_DIM + j0 + l] = fmaxf(outv + b2[j0 + l], 0.f);
}

// ---------- GEMM3 (K-parallel): one wave per batch row, all 10 classes ----------
__global__ void __launch_bounds__(256) k_gemm3(const float* __restrict__ Wfc,
                                               const float* __restrict__ bfc,
                                               const float* __restrict__ h2,
                                               float* __restrict__ out) {
    int b = blockIdx.x * 4 + (threadIdx.x >> 6);   // 0..127
    int l = threadIdx.x & 63;
    const float* hb = h2 + (size_t)b * H_DIM;
    float hv[8];
#pragma unroll
    for (int k = 0; k < 8; k++) hv[k] = hb[k * 64 + l];
    float outv = 0.f;
#pragma unroll
    for (int c = 0; c < C_DIM; c++) {
        const float* wrow = Wfc + (size_t)c * H_DIM;
        float a = 0.f;
#pragma unroll
        for (int k = 0; k < 8; k++) a = fmaf(wrow[k * 64 + l], hv[k], a);
#pragma unroll
        for (int o = 1; o < 64; o <<= 1) a += __shfl_xor(a, o);
        if (l == c) outv = a;
    }
    if (l < C_DIM) out[b * C_DIM + l] = outv + bfc[l];
}

extern "C" void kernel_launch(void* const* d_in, const int* in_sizes, int n_in,
                              void* d_out, int out_size, void* d_ws, size_t ws_size,
                              hipStream_t stream) {
    const float* x   = (const float*)d_in[0];
    const int*   ei  = (const int*)d_in[1];
    const float* ew  = (const float*)d_in[2];
    const float* W1  = (const float*)d_in[3];
    const float* b1  = (const float*)d_in[4];
    const float* W2  = (const float*)d_in[5];
    const float* b2  = (const float*)d_in[6];
    const float* Wfc = (const float*)d_in[7];
    const float* bfc = (const float*)d_in[8];
    float* out = (float*)d_out;

    const int* src = ei;
    const int* dst = ei + E_DIM;

    char* ws = (char*)d_ws;
    size_t off = 0;
    auto alloc = [&](size_t bytes) -> void* {
        void* p = ws + off;
        off = (off + bytes + 255) & ~(size_t)255;
        return p;
    };
    float* xT     = (float*)alloc((size_t)N_DIM * B_DIM * 4);          // 8 MB
    float* hT     = (float*)alloc((size_t)N_DIM * B_DIM * 4);          // 8 MB
    int2*  packed = (int2*) alloc((size_t)E_DIM * 8);                  // 8 MB
    size_t sort_bytes = (size_t)NWG * NWORD * 4 + (size_t)NGRP * NWORD * 4 + (size_t)NWORD * 4;
    size_t part_bytes = (size_t)SPLITK * H_DIM * B_DIM * 4;
    char* scratch = (char*)alloc(sort_bytes > part_bytes ? sort_bytes : part_bytes);
    float* h1     = (float*)alloc((size_t)H_DIM * B_DIM * 4);
    float* h2     = (float*)alloc((size_t)H_DIM * B_DIM * 4);
    int*   offs   = (int*)  alloc((size_t)(N_DIM + 1) * 4);
    float* dinv   = (float*)alloc((size_t)N_DIM * 4);
    uint32_t* slab   = (uint32_t*)scratch;
    uint32_t* grp    = (uint32_t*)(scratch + (size_t)NWG * NWORD * 4);
    uint32_t* binTot = (uint32_t*)(scratch + (size_t)NWG * NWORD * 4 + (size_t)NGRP * NWORD * 4);
    float* part = (float*)scratch;
    if (off > ws_size) return;

    k_transpose<<<dim3(N_DIM / 32, B_DIM / 32), dim3(32, 32), 0, stream>>>(x, xT);
    k_hist1<<<NWG, 256, 0, stream>>>(dst, slab);
    k_scanA<<<NWORD * NGRP / 256, 256, 0, stream>>>(slab, grp);
    k_scanB<<<NWORD / 256, 256, 0, stream>>>(grp, binTot);
    k_scan2b<<<1, 1024, 0, stream>>>(binTot, offs);
    k_place2<<<NWG, 256, 0, stream>>>(src, dst, ew, slab, grp, offs, packed);
    k_deg<<<N_DIM, 64, 0, stream>>>(offs, packed, dinv);
    k_norm<<<E_DIM / 256, 256, 0, stream>>>(dinv, packed);
    k_diffuse<<<N_DIM * NSLICE, 64, 0, stream>>>(xT, offs, packed, dinv, hT);
    k_gemm1<<<dim3(SPLITK, H_DIM / BM), 256, 0, stream>>>(W1, hT, part);
    k_reduce1<<<(H_DIM * B_DIM) / 256, 256, 0, stream>>>(part, b1, h1);
    k_gemm2<<<(B_DIM * (H_DIM / 8)) / 4, 256, 0, stream>>>(W2, b2, h1, h2);
    k_gemm3<<<B_DIM / 4, 256, 0, stream>>>(Wfc, bfc, h2, out);
}